// Round 1
// baseline (1713.922 us; speedup 1.0000x reference)
//
#include <hip/hip_runtime.h>
#include <stdint.h>

#define NROWS 4096   // S*B
#define HDIM  512
#define GDIM  2048   // 4*H
#define WWIN  32

typedef __attribute__((ext_vector_type(8))) short short8;
typedef __attribute__((ext_vector_type(4))) float f32x4;

__device__ __forceinline__ unsigned short f2bf(float x){
  union { float f; unsigned int u; } v; v.f = x;
  unsigned int u = v.u + 0x7fffu + ((v.u >> 16) & 1u);
  return (unsigned short)(u >> 16);
}

__device__ __forceinline__ void gld16(const void* g, void* l){
  __builtin_amdgcn_global_load_lds(
      (const __attribute__((address_space(1))) unsigned int*)g,
      (__attribute__((address_space(3))) unsigned int*)l, 16, 0, 0);
}

__device__ __forceinline__ float sigm(float x){ return 1.f/(1.f + __expf(-x)); }
__device__ __forceinline__ float tanh_f(float x){ return 1.f - 2.f/(1.f + __expf(2.f*x)); }

// ------------- double-buffered 128x128 GEMM core (bf16, BT weight layout) -----
// (kept for p0_gemm only; step_kernel now uses the 256^2 8-wave pipeline below)
__device__ __forceinline__ void gemm_tile_db(
    const char* A0, const char* A1, const char* Bsrc,
    int ldbB, int nk, int r0, int c0,
    char* smem, int wr, int wc, int lane, f32x4 acc[4][4])
{
  const int tid = threadIdx.x;
  const int oo0 = tid * 16;
  const int srow = oo0 >> 7;
  const int scb  = oo0 & 127;
  const size_t aOff = (size_t)(r0 + srow) * 1024 + scb;
  const size_t bOff = (size_t)(c0 + srow) * (size_t)ldbB + scb;

  auto STAGE = [&](int kk, int buf){
    const char* Ap = (kk < 8) ? A0 : A1;
    const size_t kbA = (size_t)(kk & 7) * 128;
    const size_t kbB = (size_t)kk * 128;
    char* AsB = smem + buf * 16384;
    char* BsB = smem + 32768 + buf * 16384;
    #pragma unroll
    for (int i = 0; i < 4; ++i){
      const size_t rstep = (size_t)i * 32;
      gld16(Ap   + aOff + rstep * 1024          + kbA, AsB + i*4096 + oo0);
      gld16(Bsrc + bOff + rstep * (size_t)ldbB  + kbB, BsB + i*4096 + oo0);
    }
  };

  STAGE(0, 0);
  __syncthreads();

  const int lr = lane & 15;
  const int lk = (lane >> 4) * 8;

  for (int kk = 0; kk < nk; ++kk){
    const int cur = kk & 1;
    if (kk + 1 < nk) STAGE(kk + 1, cur ^ 1);

    const unsigned short* As = (const unsigned short*)(smem + cur*16384);
    const unsigned short* Bs = (const unsigned short*)(smem + 32768 + cur*16384);
    short8 a[2][4], b[2][4];
    #pragma unroll
    for (int h = 0; h < 2; ++h){
      const int k32 = h * 32;
      #pragma unroll
      for (int m = 0; m < 4; ++m)
        a[h][m] = *(const short8*)(As + (64*wr + 16*m + lr)*64 + k32 + lk);
      #pragma unroll
      for (int n = 0; n < 4; ++n)
        b[h][n] = *(const short8*)(Bs + (64*wc + 16*n + lr)*64 + k32 + lk);
    }
    __builtin_amdgcn_s_setprio(1);
    #pragma unroll
    for (int h = 0; h < 2; ++h)
      #pragma unroll
      for (int m = 0; m < 4; ++m)
        #pragma unroll
        for (int n = 0; n < 4; ++n)
          acc[m][n] = __builtin_amdgcn_mfma_f32_16x16x32_bf16(a[h][m], b[h][n], acc[m][n], 0, 0, 0);
    __builtin_amdgcn_s_setprio(0);

    __syncthreads();
  }
}

// ---------------- prep: reorder weights gate-interleaved, cast bf16 -----------
__global__ void __launch_bounds__(256) prep_weights(
    const float* wih0, const float* whh0, const float* bih0, const float* bhh0,
    const float* wih1, const float* whh1, const float* bih1, const float* bhh1,
    unsigned short* BrIh0, unsigned short* Br0, unsigned short* Br1,
    float* bias0r, float* br1)
{
  const int j = blockIdx.x;
  const int g = j & 3, hd = j >> 2;
  const int r = g*512 + hd;
  for (int k = threadIdx.x; k < 512; k += 256){
    BrIh0[(size_t)j*512 + k]      = f2bf(wih0[(size_t)r*512 + k]);
    Br0  [(size_t)j*512 + k]      = f2bf(whh0[(size_t)r*512 + k]);
    Br1  [(size_t)j*1024 + k]     = f2bf(wih1[(size_t)r*512 + k]);
    Br1  [(size_t)j*1024 + 512+k] = f2bf(whh1[(size_t)r*512 + k]);
  }
  if (threadIdx.x == 0){
    bias0r[j] = bih0[r] + bhh0[r];
    br1[j]    = bih1[r] + bhh1[r];
  }
}

// ---------------- embedding gather (fp32 -> bf16) -----------------------------
__global__ void __launch_bounds__(256) gather_embed(const int* enc, const float* tbl,
                                                    unsigned short* E)
{
  const int n = blockIdx.x;
  const int idx = enc[n];
  const float* src = tbl + (size_t)idx * 512;
  unsigned short* dst = E + (size_t)n * 512;
  for (int e = threadIdx.x; e < 512; e += 256) dst[e] = f2bf(src[e]);
}

// ---------------- P0 = E @ BrIh0^T + bias0r (fp32 out, interleaved cols) ------
__global__ void __launch_bounds__(256) p0_gemm(const unsigned short* E,
                                               const unsigned short* BrIh0,
                                               const float* bias0r, float* P0)
{
  __shared__ __align__(16) char smem[65536];
  const int tid  = threadIdx.x;
  const int lane = tid & 63, wid = tid >> 6;
  const int wr = wid >> 1, wc = wid & 1;
  const int bid = blockIdx.x;
  const int r0 = (bid >> 4) * 128, c0 = (bid & 15) * 128;
  f32x4 acc[4][4] = {};
  gemm_tile_db((const char*)E, nullptr, (const char*)BrIh0, 1024, 8,
               r0, c0, smem, wr, wc, lane, acc);
  #pragma unroll
  for (int m = 0; m < 4; ++m){
    const int rowb = r0 + 64*wr + 16*m + ((lane >> 4) << 2);
    #pragma unroll
    for (int n = 0; n < 4; ++n){
      const int colb = c0 + 64*wc + 16*n + (lane & 15);
      const float bs = bias0r[colb];
      #pragma unroll
      for (int r = 0; r < 4; ++r)
        P0[(size_t)(rowb + r)*GDIM + colb] = acc[m][n][r] + bs;
    }
  }
}

// ---------------- fused super-step: L0 step tau + L1 step tau-1 ---------------
// 256x256 tile, BK=32, 8 waves (2M x 4N), per-wave 128x64 (8x4 frags).
// Ring of 4 K-tile LDS buffers (4 x 32KB = 128KB): K-tile kt staged during
// kt-2, so the per-K-tile wait is s_waitcnt vmcnt(4) -- never drains to 0 in
// the main loop (T3+T4). Per phase: {ds_read; 2x global_load_lds; barrier;
// lgkmcnt(0); sched_barrier; setprio(1); 16 MFMA; setprio(0); barrier}.
// T2 swizzle: phys 16B slot = logical ^ ((row>>1)&3); linear LDS dest +
// inverse-swizzled per-lane GLOBAL source + swizzled ds_read (rule #21).
__global__ void __launch_bounds__(512, 2) step_kernel(
    unsigned short* h0, unsigned short* h1, float* c0b, float* c1b,
    const unsigned short* Br0, const unsigned short* Br1,
    const float* P0, const float* br1, float* out, int tau, int bidOff)
{
  extern __shared__ __align__(16) char smem[];

  // XCD-balanced bijective swizzle: each XCD gets 16 L0 + 16 L1 contiguous
  // tiles (grid=256), or 16 contiguous tiles (grid=128). 256%8==0 -> bijective.
  const int x = blockIdx.x & 7, kq = blockIdx.x >> 3;
  int wk;
  if (gridDim.x == 256) wk = ((kq & 1) << 7) + x * 16 + (kq >> 1);
  else                  wk = x * 16 + kq;
  wk += bidOff;

  const bool L1 = (wk >= 128);
  const int t  = L1 ? (tau - 1) : tau;
  const int pr = (tau + 1) & 1, pw = tau & 1;
  const int lb = L1 ? (wk - 128) : wk;
  const int r0  = (lb >> 3) * 256;
  const int c0v = (lb & 7) * 256;

  const int tid  = threadIdx.x;
  const int lane = tid & 63;
  const int wid  = tid >> 6;
  const int wm = wid >> 2, wn = wid & 3;
  const int lr = lane & 15, sl = lane >> 4;

  const unsigned short* hA0 = h0 + (size_t)pr * (NROWS*HDIM);
  const unsigned short* hA1 = h1 + (size_t)pr * (NROWS*HDIM);
  const char* Bp  = (const char*)(L1 ? Br1 : Br0);
  const int  ldbB = L1 ? 2048 : 1024;
  const int  nkt  = L1 ? 32 : 16;

  // staging thread-constants: chunk c covers rows c*128 + (tid>>2), 16B slot
  // tid&3; source slot inverse-swizzled so swizzled read finds logical data.
  const int srow  = tid >> 2;
  const int sbyte = ((tid & 3) ^ ((tid >> 3) & 3)) << 4;
  // read lane-constants: phys slot = sl ^ ((row>>1)&3) = sl ^ ((lr>>1)&3)
  const int ph    = (sl ^ ((lr >> 1) & 3)) << 4;
  const int laneA = (wm*128 + lr) * 64 + ph;
  const int laneB = (wn*64  + lr) * 64 + ph;

  auto STAGE_A = [&](int kt2, int c){
    const char* Ap; int kB;
    if (!L1 || kt2 < 16){ Ap = (const char*)hA0; kB = kt2 * 64; }
    else                { Ap = (const char*)hA1; kB = (kt2 - 16) * 64; }
    gld16(Ap + (size_t)(r0 + c*128 + srow) * 1024 + kB + sbyte,
          smem + (size_t)(kt2 & 3) * 32768 + c*8192 + tid*16);
  };
  auto STAGE_B = [&](int kt2, int c){
    gld16(Bp + (size_t)(c0v + c*128 + srow) * (size_t)ldbB + kt2*64 + sbyte,
          smem + (size_t)(kt2 & 3) * 32768 + 16384 + c*8192 + tid*16);
  };

  f32x4 acc[8][4] = {};

  // prologue: stage kt=0 and kt=1; wait kt0 complete (4 newer in flight)
  STAGE_A(0,0); STAGE_A(0,1); STAGE_B(0,0); STAGE_B(0,1);
  STAGE_A(1,0); STAGE_A(1,1); STAGE_B(1,0); STAGE_B(1,1);
  asm volatile("s_waitcnt vmcnt(4)" ::: "memory");
  __builtin_amdgcn_s_barrier();

  for (int kt = 0; kt < nkt; ++kt){
    const char* bufp = smem + (size_t)(kt & 3) * 32768;
    const bool st = (kt + 2) < nkt;
    short8 a0[4], a1[4], b[4];

    // ---- phase 0: frags m0-3 x n0-3 ----
    #pragma unroll
    for (int m = 0; m < 4; ++m) a0[m] = *(const short8*)(bufp + laneA + m*1024);
    #pragma unroll
    for (int n = 0; n < 4; ++n) b[n]  = *(const short8*)(bufp + 16384 + laneB + n*1024);
    if (st){ STAGE_A(kt+2, 0); STAGE_A(kt+2, 1); }
    __builtin_amdgcn_s_barrier();
    asm volatile("s_waitcnt lgkmcnt(0)" ::: "memory");
    __builtin_amdgcn_sched_barrier(0);
    __builtin_amdgcn_s_setprio(1);
    #pragma unroll
    for (int m = 0; m < 4; ++m)
      #pragma unroll
      for (int n = 0; n < 4; ++n)
        acc[m][n] = __builtin_amdgcn_mfma_f32_16x16x32_bf16(a0[m], b[n], acc[m][n], 0, 0, 0);
    __builtin_amdgcn_s_setprio(0);
    __builtin_amdgcn_s_barrier();

    // ---- phase 1: frags m4-7 x n0-3 ----
    #pragma unroll
    for (int m = 0; m < 4; ++m) a1[m] = *(const short8*)(bufp + laneA + (4+m)*1024);
    if (st){
      STAGE_B(kt+2, 0); STAGE_B(kt+2, 1);
      asm volatile("s_waitcnt vmcnt(4)" ::: "memory");  // kt+1 fully staged
    } else {
      asm volatile("s_waitcnt vmcnt(0)" ::: "memory");  // tail: drain
    }
    __builtin_amdgcn_s_barrier();
    asm volatile("s_waitcnt lgkmcnt(0)" ::: "memory");
    __builtin_amdgcn_sched_barrier(0);
    __builtin_amdgcn_s_setprio(1);
    #pragma unroll
    for (int m = 0; m < 4; ++m)
      #pragma unroll
      for (int n = 0; n < 4; ++n)
        acc[4+m][n] = __builtin_amdgcn_mfma_f32_16x16x32_bf16(a1[m], b[n], acc[4+m][n], 0, 0, 0);
    __builtin_amdgcn_s_setprio(0);
    __builtin_amdgcn_s_barrier();
  }

  // ---------------- epilogue: LSTM pointwise, 4 column-passes ----------------
  float* GLDS = (float*)smem;
  const int GST = 68;   // padded fp32 stride (256 rows x 68 x 4B = 69632 B)
  float* cbuf = L1 ? c1b : c0b;
  unsigned short* hw = (L1 ? h1 : h0) + (size_t)pw * (NROWS*HDIM);
  const bool finalStep = (L1 && t == 32);

  for (int pass = 0; pass < 4; ++pass){
    __syncthreads();
    if (wn == pass){
      #pragma unroll
      for (int m = 0; m < 8; ++m){
        const int rowb = wm*128 + m*16 + (sl << 2);
        #pragma unroll
        for (int n = 0; n < 4; ++n){
          const int colb = n*16 + lr;
          const f32x4 v = acc[m][n];
          #pragma unroll
          for (int r = 0; r < 4; ++r)
            GLDS[(rowb + r)*GST + colb] = v[r];
        }
      }
    }
    __syncthreads();
    #pragma unroll
    for (int it = 0; it < 8; ++it){
      const int cid = it*512 + tid;            // 4096 cells: 256 rows x 16 hd
      const int row = cid >> 4;
      const int l   = cid & 15;
      const int rowg = r0 + row;
      const int hd   = (c0v >> 2) + pass*16 + l;
      float4 gv = *(const float4*)&GLDS[row*GST + 4*l];
      float gi = gv.x, gf = gv.y, gg = gv.z, go = gv.w;
      const int s  = rowg >> 3;
      const int bb = rowg & 7;
      const int pos = s - WWIN + t;
      if (!L1){
        const int p0r = (pos < 0 ? 0 : pos)*8 + bb;
        float4 pv = *(const float4*)&P0[(size_t)p0r*GDIM + 4*hd];
        gi += pv.x; gf += pv.y; gg += pv.z; go += pv.w;
      } else {
        float4 bv = *(const float4*)&br1[4*hd];
        gi += bv.x; gf += bv.y; gg += bv.z; go += bv.w;
      }
      const size_t sidx = (size_t)rowg*HDIM + hd;
      float cp = cbuf[sidx];
      float i_ = sigm(gi), f_ = sigm(gf), g_ = tanh_f(gg), o_ = sigm(go);
      float cn = f_*cp + i_*g_;
      float hn = o_*tanh_f(cn);
      if (pos < 0){ cn = 0.f; hn = 0.f; }
      cbuf[sidx] = cn;
      if (finalStep) out[sidx] = hn;
      else           hw[sidx]  = f2bf(hn);
    }
  }
}

extern "C" void kernel_launch(void* const* d_in, const int* in_sizes, int n_in,
                              void* d_out, int out_size, void* d_ws, size_t ws_size,
                              hipStream_t stream)
{
  const int*   enc  = (const int*)d_in[0];
  const float* tbl  = (const float*)d_in[1];
  const float* wih0 = (const float*)d_in[2];
  const float* whh0 = (const float*)d_in[3];
  const float* bih0 = (const float*)d_in[4];
  const float* bhh0 = (const float*)d_in[5];
  const float* wih1 = (const float*)d_in[6];
  const float* whh1 = (const float*)d_in[7];
  const float* bih1 = (const float*)d_in[8];
  const float* bhh1 = (const float*)d_in[9];
  float* out = (float*)d_out;

  char* ws = (char*)d_ws;
  size_t off = 0;
  auto alloc = [&](size_t bytes){
    char* p = ws + off; off += (bytes + 255) & ~(size_t)255; return p;
  };
  unsigned short* E     = (unsigned short*)alloc((size_t)NROWS*512*2);
  unsigned short* BrIh0 = (unsigned short*)alloc((size_t)GDIM*512*2);
  unsigned short* Br0   = (unsigned short*)alloc((size_t)GDIM*512*2);
  unsigned short* Br1   = (unsigned short*)alloc((size_t)GDIM*1024*2);
  float* bias0r = (float*)alloc(GDIM*4);
  float* br1    = (float*)alloc(GDIM*4);
  float* P0     = (float*)alloc((size_t)NROWS*GDIM*4);
  unsigned short* h0 = (unsigned short*)alloc((size_t)2*NROWS*HDIM*2);
  unsigned short* h1 = (unsigned short*)alloc((size_t)2*NROWS*HDIM*2);
  float* c0 = (float*)alloc((size_t)NROWS*HDIM*4);
  float* c1 = (float*)alloc((size_t)NROWS*HDIM*4);
  if (off > ws_size) return;  // workspace too small — would need fallback

  // allow 128 KB dynamic LDS for step_kernel (host-side attr, capture-safe)
  (void)hipFuncSetAttribute(reinterpret_cast<const void*>(step_kernel),
                            hipFuncAttributeMaxDynamicSharedMemorySize, 131072);

  // zero recurrent state (h0,h1,c0,c1 are contiguous: 8+8+8+8 MB)
  hipMemsetAsync(h0, 0, (size_t)33554432, stream);

  prep_weights<<<2048, 256, 0, stream>>>(wih0, whh0, bih0, bhh0,
                                         wih1, whh1, bih1, bhh1,
                                         BrIh0, Br0, Br1, bias0r, br1);
  gather_embed<<<4096, 256, 0, stream>>>(enc, tbl, E);
  p0_gemm<<<512, 256, 0, stream>>>(E, BrIh0, bias0r, P0);
  for (int tau = 0; tau <= 33; ++tau){
    const int grid = (tau == 0 || tau == 33) ? 128 : 256;
    const int boff = (tau == 33) ? 128 : 0;
    step_kernel<<<grid, 512, 131072, stream>>>(h0, h1, c0, c1, Br0, Br1,
                                               P0, br1, out, tau, boff);
  }
}